// Round 1
// baseline (402.522 us; speedup 1.0000x reference)
//
#include <hip/hip_runtime.h>
#include <hip/hip_bf16.h>

typedef unsigned short u16;
typedef __attribute__((ext_vector_type(8))) short bf16x8;
typedef __attribute__((ext_vector_type(4))) float f32x4;

#define N_TOK 4096
#define DMODEL 3072
#define NH 16
#define DHEAD 64
#define INNER 1024
#define SCALE_LOG2E 0.18033688011112042f  /* (1/8) * log2(e) */

__device__ __forceinline__ u16 f2bf(float f) {
    union { float f; unsigned u; } un; un.f = f;
    unsigned r = un.u + 0x7fffu + ((un.u >> 16) & 1u);
    return (u16)(r >> 16);
}
__device__ __forceinline__ float bf2f(u16 u) {
    union { unsigned u; float f; } x; x.u = ((unsigned)u) << 16; return x.f;
}
// pack two f32 -> two bf16 (round-half-up) in 3 VALU ops; a -> low 16
__device__ __forceinline__ unsigned pk2bf(float a, float b) {
    union { float f; unsigned u; } ua, ub; ua.f = a; ub.f = b;
    return __builtin_amdgcn_perm(ub.u + 0x8000u, ua.u + 0x8000u, 0x07060302u);
}
__device__ __forceinline__ void load_lds16(const u16* g, u16* l) {
    __builtin_amdgcn_global_load_lds(
        (const __attribute__((address_space(1))) unsigned int*)g,
        (__attribute__((address_space(3))) unsigned int*)l, 16, 0, 0);
}

// ---------------- LayerNorm: x f32 [4096,3072] -> xn bf16 ----------------
__global__ __launch_bounds__(256) void ln_kernel(const float* __restrict__ x,
                                                 const float* __restrict__ g,
                                                 const float* __restrict__ b,
                                                 u16* __restrict__ xn) {
    int row = blockIdx.x;
    int tid = threadIdx.x;
    const float4* xr = (const float4*)(x + (size_t)row * DMODEL);
    float4 v[3];
    float s = 0.f, ss = 0.f;
#pragma unroll
    for (int i = 0; i < 3; ++i) {
        v[i] = xr[i * 256 + tid];
        s  += v[i].x + v[i].y + v[i].z + v[i].w;
        ss += v[i].x * v[i].x + v[i].y * v[i].y + v[i].z * v[i].z + v[i].w * v[i].w;
    }
#pragma unroll
    for (int off = 32; off; off >>= 1) {
        s  += __shfl_xor(s, off);
        ss += __shfl_xor(ss, off);
    }
    __shared__ float red[8];
    int wid = tid >> 6, lane = tid & 63;
    if (lane == 0) { red[wid] = s; red[wid + 4] = ss; }
    __syncthreads();
    s  = red[0] + red[1] + red[2] + red[3];
    ss = red[4] + red[5] + red[6] + red[7];
    float mean = s * (1.f / DMODEL);
    float var  = ss * (1.f / DMODEL) - mean * mean;
    float rstd = rsqrtf(var + 1e-5f);
    ushort4* orow = (ushort4*)(xn + (size_t)row * DMODEL);
#pragma unroll
    for (int i = 0; i < 3; ++i) {
        float4 gg = ((const float4*)g)[i * 256 + tid];
        float4 bb = ((const float4*)b)[i * 256 + tid];
        ushort4 o;
        o.x = f2bf((v[i].x - mean) * rstd * gg.x + bb.x);
        o.y = f2bf((v[i].y - mean) * rstd * gg.y + bb.y);
        o.z = f2bf((v[i].z - mean) * rstd * gg.z + bb.z);
        o.w = f2bf((v[i].w - mean) * rstd * gg.w + bb.w);
        orow[i * 256 + tid] = o;
    }
}

// ---------------- f32 -> bf16 convert ----------------
__global__ __launch_bounds__(256) void cvt_bf16(const float* __restrict__ in,
                                                u16* __restrict__ out, int n4) {
    int i = blockIdx.x * 256 + threadIdx.x;
    if (i < n4) {
        float4 v = ((const float4*)in)[i];
        ushort4 o;
        o.x = f2bf(v.x); o.y = f2bf(v.y); o.z = f2bf(v.z); o.w = f2bf(v.w);
        ((ushort4*)out)[i] = o;
    }
}

// ---------------- GEMM C = A * B^T ; A[M,K], B[N,K] bf16, C f32 or bf16 ---
template <int CBF16>
__global__ __launch_bounds__(256) void gemm_bt(const u16* __restrict__ A,
                                               const u16* __restrict__ B,
                                               void* __restrict__ C,
                                               int M, int Nn, int K) {
    __shared__ u16 As[128 * 32];
    __shared__ u16 Bs[128 * 32];
    int tid = threadIdx.x;
    int lane = tid & 63, wid = tid >> 6;
    int wm = wid >> 1, wn = wid & 1;
    int l15 = lane & 15, quad = lane >> 4;
    int m0 = blockIdx.y * 128, n0 = blockIdx.x * 128;

    f32x4 zero4 = {0.f, 0.f, 0.f, 0.f};
    f32x4 acc[4][4];
#pragma unroll
    for (int i = 0; i < 4; ++i)
#pragma unroll
        for (int j = 0; j < 4; ++j) acc[i][j] = zero4;

    const u16* Ab = A + (size_t)m0 * K;
    const u16* Bb = B + (size_t)n0 * K;
    int row0 = tid >> 2, c0 = (((tid & 3) ^ ((lane >> 3) & 3)) * 8);  // swizzled col
    int row1 = row0 + 64;
    int rsw = (l15 >> 1) & 3;

    for (int k0 = 0; k0 < K; k0 += 32) {
        load_lds16(Ab + (size_t)row0 * K + k0 + c0, &As[wid * 512]);
        load_lds16(Ab + (size_t)row1 * K + k0 + c0, &As[2048 + wid * 512]);
        load_lds16(Bb + (size_t)row0 * K + k0 + c0, &Bs[wid * 512]);
        load_lds16(Bb + (size_t)row1 * K + k0 + c0, &Bs[2048 + wid * 512]);
        __syncthreads();
        bf16x8 a[4], b[4];
#pragma unroll
        for (int t = 0; t < 4; ++t) {
            a[t] = *(const bf16x8*)&As[(wm * 64 + t * 16 + l15) * 32 + ((quad ^ rsw) * 8)];
            b[t] = *(const bf16x8*)&Bs[(wn * 64 + t * 16 + l15) * 32 + ((quad ^ rsw) * 8)];
        }
#pragma unroll
        for (int mt = 0; mt < 4; ++mt)
#pragma unroll
            for (int nt = 0; nt < 4; ++nt)
                acc[mt][nt] = __builtin_amdgcn_mfma_f32_16x16x32_bf16(a[mt], b[nt], acc[mt][nt], 0, 0, 0);
        __syncthreads();
    }
#pragma unroll
    for (int mt = 0; mt < 4; ++mt)
#pragma unroll
        for (int nt = 0; nt < 4; ++nt)
#pragma unroll
            for (int r = 0; r < 4; ++r) {
                int rr = m0 + wm * 64 + mt * 16 + quad * 4 + r;
                int cc = n0 + wn * 64 + nt * 16 + l15;
                if (CBF16)
                    ((u16*)C)[(size_t)rr * Nn + cc] = f2bf(acc[mt][nt][r]);
                else
                    ((float*)C)[(size_t)rr * Nn + cc] = acc[mt][nt][r];
            }
}

// ---------------- RoPE on q,k + reshape to [H,N,DH] ----------------
// Q is pre-scaled by (1/8)*log2(e) so flash's exp2 needs no multiply.
__global__ __launch_bounds__(256) void rope_qk(const u16* __restrict__ qkv,
                                               const float* __restrict__ pe,
                                               u16* __restrict__ Qr,
                                               u16* __restrict__ Kr) {
    int n = blockIdx.x;
    int tid = threadIdx.x;
    const u16* qrow = qkv + (size_t)n * DMODEL;
    const float4* pen = (const float4*)(pe + (size_t)n * 128);
#pragma unroll
    for (int it = 0; it < 2; ++it) {
        int p = it * 256 + tid;      // pair index 0..511
        int h = p >> 5, i = p & 31;
        float4 w = pen[i];
        size_t obase = ((size_t)h * N_TOK + n) * DHEAD + 2 * i;
        unsigned qq = *(const unsigned*)&qrow[h * 64 + 2 * i];
        float q0 = bf2f((u16)qq), q1 = bf2f((u16)(qq >> 16));
        *(unsigned*)&Qr[obase] = pk2bf((w.x * q0 + w.y * q1) * SCALE_LOG2E,
                                       (w.z * q0 + w.w * q1) * SCALE_LOG2E);
        unsigned kk = *(const unsigned*)&qrow[INNER + h * 64 + 2 * i];
        float k0 = bf2f((u16)kk), k1 = bf2f((u16)(kk >> 16));
        *(unsigned*)&Kr[obase] = pk2bf(w.x * k0 + w.y * k1, w.z * k0 + w.w * k1);
    }
}

// ---------------- V transpose: Vt[h][d][n] = qkv[n][2048 + h*64 + d] ------
__global__ __launch_bounds__(256) void v_transpose(const u16* __restrict__ qkv,
                                                   u16* __restrict__ Vt) {
    __shared__ u16 t[64][65];
    int n0 = blockIdx.x * 64;
    int h = blockIdx.y;
    int tid = threadIdx.x;
#pragma unroll
    for (int it = 0; it < 4; ++it) {
        int nr = it * 16 + (tid >> 4);
        int dc = (tid & 15) * 4;
        ushort4 v = *(const ushort4*)&qkv[(size_t)(n0 + nr) * DMODEL + 2 * INNER + h * 64 + dc];
        t[dc + 0][nr] = v.x; t[dc + 1][nr] = v.y; t[dc + 2][nr] = v.z; t[dc + 3][nr] = v.w;
    }
    __syncthreads();
#pragma unroll
    for (int it = 0; it < 4; ++it) {
        int dr = it * 16 + (tid >> 4);
        int nc = (tid & 15) * 4;
        ushort4 v;
        v.x = t[dr][nc]; v.y = t[dr][nc + 1]; v.z = t[dr][nc + 2]; v.w = t[dr][nc + 3];
        *(ushort4*)&Vt[((size_t)h * 64 + dr) * N_TOK + n0 + nc] = v;
    }
}

// ---------------- Flash attention (fixed-bias softmax, no online max) -----
// grid (32 qtiles, 16 heads); 256 thr = 4 waves; wave owns 32 q-rows.
// Q pre-scaled so S^T (bf16 MFMA) is directly the exp2 argument.
// p = exp2(s) raw, carried in BF16 (range 2^127 — raw p can reach ~2^30,
// which overflows f16; f16 attempt failed R5). l via ones-row MFMA.
__global__ __launch_bounds__(256, 2) void flash_attn(const u16* __restrict__ Q,
                                                     const u16* __restrict__ K,
                                                     const u16* __restrict__ Vt,
                                                     u16* __restrict__ O) {
    __shared__ u16 lds_all[16384];           // 32 KB
    u16* Ks = lds_all;                       // [key 64][chunk 8][8]  (8 KB) bf16
    u16* Vs = lds_all + 4096;                // [d 64][chunk 8][8]    (8 KB) bf16
    int tid = threadIdx.x, lane = tid & 63, wid = tid >> 6;
    u16* Ps = lds_all + 8192 + wid * 2048;   // per-wave [q 32][chunk 8][8] (4 KB) bf16
    int l15 = lane & 15, quad = lane >> 4;
    int sw = l15 & 7;
    int h = blockIdx.y;
    int q0 = blockIdx.x * 128 + wid * 32;
    const u16* Qh = Q + (size_t)h * N_TOK * DHEAD;
    const u16* Kh = K + (size_t)h * N_TOK * DHEAD;
    const u16* Vh = Vt + (size_t)h * DHEAD * N_TOK;

    f32x4 zero4 = {0.f, 0.f, 0.f, 0.f};
    bf16x8 ones;
#pragma unroll
    for (int i = 0; i < 8; ++i) ones[i] = (short)0x3F80;  // bf16 1.0

    // Q fragments (B operand): B[n=q=l15][k=dhead]
    bf16x8 aq[2][2];
#pragma unroll
    for (int mtQ = 0; mtQ < 2; ++mtQ)
#pragma unroll
        for (int kc = 0; kc < 2; ++kc)
            aq[mtQ][kc] = *(const bf16x8*)&Qh[(size_t)(q0 + mtQ * 16 + l15) * DHEAD + kc * 32 + quad * 8];

    f32x4 o[2][4], lacc[2];
#pragma unroll
    for (int mtQ = 0; mtQ < 2; ++mtQ) {
#pragma unroll
        for (int dt = 0; dt < 4; ++dt) o[mtQ][dt] = zero4;
        lacc[mtQ] = zero4;
    }

    // staging: wave stages rows [wid*16, wid*16+16); XOR swizzle on global col
    int rbase = wid * 16;
    int rowoff = lane >> 3;                      // 0..7
    int csw = ((lane & 7) ^ rowoff) * 8;         // swizzled source column (u16)

    for (int kt = 0; kt < N_TOK; kt += 64) {
        load_lds16(&Kh[(size_t)(kt + rbase + rowoff) * DHEAD + csw], &Ks[rbase * 64]);
        load_lds16(&Kh[(size_t)(kt + rbase + 8 + rowoff) * DHEAD + csw], &Ks[(rbase + 8) * 64]);
        load_lds16(&Vh[(size_t)(rbase + rowoff) * N_TOK + kt + csw], &Vs[rbase * 64]);
        load_lds16(&Vh[(size_t)(rbase + 8 + rowoff) * N_TOK + kt + csw], &Vs[(rbase + 8) * 64]);
        __syncthreads();

        bf16x8 bk[4][2], av[4][2];
#pragma unroll
        for (int t = 0; t < 4; ++t)
#pragma unroll
            for (int kc = 0; kc < 2; ++kc) {
                int off = (t * 16 + l15) * 64 + (((kc * 4 + quad) ^ sw) * 8);
                bk[t][kc] = *(const bf16x8*)&Ks[off];
                av[t][kc] = *(const bf16x8*)&Vs[off];
            }
        __syncthreads();

#pragma unroll
        for (int mtQ = 0; mtQ < 2; ++mtQ) {
            // S^T: rows=key, cols=q (already in log2-exp domain via Q pre-scale)
            f32x4 s[4];
#pragma unroll
            for (int ntK = 0; ntK < 4; ++ntK) {
                f32x4 t0 = __builtin_amdgcn_mfma_f32_16x16x32_bf16(bk[ntK][0], aq[mtQ][0], zero4, 0, 0, 0);
                s[ntK] = __builtin_amdgcn_mfma_f32_16x16x32_bf16(bk[ntK][1], aq[mtQ][1], t0, 0, 0, 0);
            }
            // p = exp2(s); pack to bf16 and store P^T (swizzled chunks)
#pragma unroll
            for (int ntK = 0; ntK < 4; ++ntK) {
                uint2 pv;
                pv.x = pk2bf(__builtin_amdgcn_exp2f(s[ntK][0]), __builtin_amdgcn_exp2f(s[ntK][1]));
                pv.y = pk2bf(__builtin_amdgcn_exp2f(s[ntK][2]), __builtin_amdgcn_exp2f(s[ntK][3]));
                int pc = (ntK * 2 + (quad >> 1)) ^ sw;
                *(uint2*)&Ps[(mtQ * 16 + l15) * 64 + pc * 8 + (quad & 1) * 4] = pv;
            }
            // reload as B operand: B[n=q=l15][k=key]
            bf16x8 bp0 = *(const bf16x8*)&Ps[(mtQ * 16 + l15) * 64 + ((quad ^ sw) * 8)];
            bf16x8 bp1 = *(const bf16x8*)&Ps[(mtQ * 16 + l15) * 64 + (((4 + quad) ^ sw) * 8)];
            // l += sum_k P (ones-row MFMA; every lane gets l(q) in all 4 elems)
            lacc[mtQ] = __builtin_amdgcn_mfma_f32_16x16x32_bf16(ones, bp0, lacc[mtQ], 0, 0, 0);
            lacc[mtQ] = __builtin_amdgcn_mfma_f32_16x16x32_bf16(ones, bp1, lacc[mtQ], 0, 0, 0);
#pragma unroll
            for (int dt = 0; dt < 4; ++dt) {
                o[mtQ][dt] = __builtin_amdgcn_mfma_f32_16x16x32_bf16(av[dt][0], bp0, o[mtQ][dt], 0, 0, 0);
                o[mtQ][dt] = __builtin_amdgcn_mfma_f32_16x16x32_bf16(av[dt][1], bp1, o[mtQ][dt], 0, 0, 0);
            }
        }
    }

    // epilogue: transpose O^T -> O via per-wave LDS scratch, then coalesced write
    __syncthreads();
    u16* scratch = lds_all + wid * 2048;     // [q 32][d 64]
#pragma unroll
    for (int mtQ = 0; mtQ < 2; ++mtQ) {
        float rl = 1.f / lacc[mtQ][0];
#pragma unroll
        for (int dt = 0; dt < 4; ++dt) {
            uint2 ov;
            ov.x = pk2bf(o[mtQ][dt][0] * rl, o[mtQ][dt][1] * rl);
            ov.y = pk2bf(o[mtQ][dt][2] * rl, o[mtQ][dt][3] * rl);
            *(uint2*)&scratch[(mtQ * 16 + l15) * 64 + dt * 16 + quad * 4] = ov;
        }
    }
#pragma unroll
    for (int p = 0; p < 4; ++p) {
        int q_local = p * 8 + (lane >> 3);
        int dcol = (lane & 7) * 8;
        bf16x8 v = *(const bf16x8*)&scratch[q_local * 64 + dcol];
        *(bf16x8*)&O[(size_t)(q0 + q_local) * INNER + h * 64 + dcol] = v;
    }
}

extern "C" void kernel_launch(void* const* d_in, const int* in_sizes, int n_in,
                              void* d_out, int out_size, void* d_ws, size_t ws_size,
                              hipStream_t stream) {
    const float* x     = (const float*)d_in[0];
    const float* pe    = (const float*)d_in[1];
    const float* w_qkv = (const float*)d_in[2];
    const float* w_out = (const float*)d_in[3];
    const float* ln_g  = (const float*)d_in[4];
    const float* ln_b  = (const float*)d_in[5];
    float* out = (float*)d_out;

    char* ws = (char*)d_ws;
    u16* xn  = (u16*)ws;  ws += (size_t)N_TOK * DMODEL * 2;
    u16* wq  = (u16*)ws;  ws += (size_t)3 * INNER * DMODEL * 2;
    u16* wo  = (u16*)ws;  ws += (size_t)DMODEL * INNER * 2;
    u16* qkv = (u16*)ws;  ws += (size_t)N_TOK * DMODEL * 2;
    u16* Qr  = (u16*)ws;  ws += (size_t)NH * N_TOK * DHEAD * 2;
    u16* Kr  = (u16*)ws;  ws += (size_t)NH * N_TOK * DHEAD * 2;
    u16* Vt  = (u16*)ws;  ws += (size_t)NH * DHEAD * N_TOK * 2;
    u16* Ob  = (u16*)ws;  ws += (size_t)N_TOK * INNER * 2;

    ln_kernel<<<N_TOK, 256, 0, stream>>>(x, ln_g, ln_b, xn);
    {
        int n4 = 3 * INNER * DMODEL / 4;
        cvt_bf16<<<(n4 + 255) / 256, 256, 0, stream>>>(w_qkv, wq, n4);
    }
    {
        int n4 = DMODEL * INNER / 4;
        cvt_bf16<<<(n4 + 255) / 256, 256, 0, stream>>>(w_out, wo, n4);
    }
    gemm_bt<1><<<dim3(DMODEL / 128, N_TOK / 128), 256, 0, stream>>>(xn, wq, qkv, N_TOK, DMODEL, DMODEL);
    rope_qk<<<N_TOK, 256, 0, stream>>>(qkv, pe, Qr, Kr);
    v_transpose<<<dim3(N_TOK / 64, NH), 256, 0, stream>>>(qkv, Vt);
    flash_attn<<<dim3(N_TOK / 128, NH), 256, 0, stream>>>(Qr, Kr, Vt, Ob);
    gemm_bt<0><<<dim3(DMODEL / 128, N_TOK / 128), 256, 0, stream>>>(Ob, wo, out, N_TOK, DMODEL, INNER);
}

// Round 2
// 375.364 us; speedup vs baseline: 1.0724x; 1.0724x over previous
//
#include <hip/hip_runtime.h>
#include <hip/hip_bf16.h>

typedef unsigned short u16;
typedef __attribute__((ext_vector_type(8))) short bf16x8;
typedef __attribute__((ext_vector_type(4))) float f32x4;

#define N_TOK 4096
#define DMODEL 3072
#define NH 16
#define DHEAD 64
#define INNER 1024
#define SCALE_LOG2E 0.18033688011112042f  /* (1/8) * log2(e) */

__device__ __forceinline__ u16 f2bf(float f) {
    union { float f; unsigned u; } un; un.f = f;
    unsigned r = un.u + 0x7fffu + ((un.u >> 16) & 1u);
    return (u16)(r >> 16);
}
__device__ __forceinline__ float bf2f(u16 u) {
    union { unsigned u; float f; } x; x.u = ((unsigned)u) << 16; return x.f;
}
// pack two f32 -> two bf16 (round-half-up) in 3 VALU ops; a -> low 16
__device__ __forceinline__ unsigned pk2bf(float a, float b) {
    union { float f; unsigned u; } ua, ub; ua.f = a; ub.f = b;
    return __builtin_amdgcn_perm(ub.u + 0x8000u, ua.u + 0x8000u, 0x07060302u);
}
__device__ __forceinline__ void load_lds16(const u16* g, u16* l) {
    __builtin_amdgcn_global_load_lds(
        (const __attribute__((address_space(1))) unsigned int*)g,
        (__attribute__((address_space(3))) unsigned int*)l, 16, 0, 0);
}

// ---------------- LayerNorm: x f32 [4096,3072] -> xn bf16 ----------------
__global__ __launch_bounds__(256) void ln_kernel(const float* __restrict__ x,
                                                 const float* __restrict__ g,
                                                 const float* __restrict__ b,
                                                 u16* __restrict__ xn) {
    int row = blockIdx.x;
    int tid = threadIdx.x;
    const float4* xr = (const float4*)(x + (size_t)row * DMODEL);
    float4 v[3];
    float s = 0.f, ss = 0.f;
#pragma unroll
    for (int i = 0; i < 3; ++i) {
        v[i] = xr[i * 256 + tid];
        s  += v[i].x + v[i].y + v[i].z + v[i].w;
        ss += v[i].x * v[i].x + v[i].y * v[i].y + v[i].z * v[i].z + v[i].w * v[i].w;
    }
#pragma unroll
    for (int off = 32; off; off >>= 1) {
        s  += __shfl_xor(s, off);
        ss += __shfl_xor(ss, off);
    }
    __shared__ float red[8];
    int wid = tid >> 6, lane = tid & 63;
    if (lane == 0) { red[wid] = s; red[wid + 4] = ss; }
    __syncthreads();
    s  = red[0] + red[1] + red[2] + red[3];
    ss = red[4] + red[5] + red[6] + red[7];
    float mean = s * (1.f / DMODEL);
    float var  = ss * (1.f / DMODEL) - mean * mean;
    float rstd = rsqrtf(var + 1e-5f);
    ushort4* orow = (ushort4*)(xn + (size_t)row * DMODEL);
#pragma unroll
    for (int i = 0; i < 3; ++i) {
        float4 gg = ((const float4*)g)[i * 256 + tid];
        float4 bb = ((const float4*)b)[i * 256 + tid];
        ushort4 o;
        o.x = f2bf((v[i].x - mean) * rstd * gg.x + bb.x);
        o.y = f2bf((v[i].y - mean) * rstd * gg.y + bb.y);
        o.z = f2bf((v[i].z - mean) * rstd * gg.z + bb.z);
        o.w = f2bf((v[i].w - mean) * rstd * gg.w + bb.w);
        orow[i * 256 + tid] = o;
    }
}

// ---------------- f32 -> bf16 convert ----------------
__global__ __launch_bounds__(256) void cvt_bf16(const float* __restrict__ in,
                                                u16* __restrict__ out, int n4) {
    int i = blockIdx.x * 256 + threadIdx.x;
    if (i < n4) {
        float4 v = ((const float4*)in)[i];
        ushort4 o;
        o.x = f2bf(v.x); o.y = f2bf(v.y); o.z = f2bf(v.z); o.w = f2bf(v.w);
        ((ushort4*)out)[i] = o;
    }
}

// ============ GEMM 256x256 8-phase (T2+T3+T4+T5), C = A * B^T ============
// A[M,K], B[N,K] bf16. 512 thr = 8 waves (2M x 4N); per-wave C = 128x64.
// BK=64, double-buffered 128 KiB LDS. Per K-tile: 4 phases (quadrant p reads
// A-rows [32p,32p+32) of the wave panel; B-frags loaded in phase 0).
// Staging: half-tiles (A0=qgroups0,1 / A1=qgroups2,3 / B0=rows0-127 /
// B1=rows128-255), one half-tile (2x global_load_lds 16B) per phase:
//   ph1:(t+1).A1  ph2:(t+2).B0  ph3:(t+2).B1  ph4:(t+2).A0 +vmcnt(6)
//   ph5:(t+2).A1  ph6:(t+3).B0  ph7:(t+3).B1  ph8:(t+3).A0 +vmcnt(6)
// Every overwritten region is sealed >=1 barrier after its last ds_read
// (per-wave lgkmcnt(0) precedes each end-of-phase barrier).
// LDS swizzle: chunk ^= (row&7) on 16B chunks, applied on pre-swizzled
// global source AND ds_read (both-sides, rule #21) -> conflict-free b128.

#define VM6 asm volatile("s_waitcnt vmcnt(6)" ::: "memory")
#define VM0 asm volatile("s_waitcnt vmcnt(0)" ::: "memory")
#define LGK8 asm volatile("s_waitcnt lgkmcnt(8)" ::: "memory")
#define NOPS ((void)0)

#define ST_A(d, h, t) do { \
    load_lds16(pA##h##0 + (size_t)(t) * 64, &lds[(d) * 16384 + (h) * 8192 + dq]); \
    load_lds16(pA##h##1 + (size_t)(t) * 64, &lds[(d) * 16384 + (h) * 8192 + dq + 512]); \
  } while (0)
#define ST_B(d, h, t) do { \
    load_lds16(pB##h##0 + (size_t)(t) * 64, &lds[32768 + (d) * 16384 + (h) * 8192 + dq]); \
    load_lds16(pB##h##1 + (size_t)(t) * 64, &lds[32768 + (d) * 16384 + (h) * 8192 + dq + 512]); \
  } while (0)

#define PHASE(d, p, STAGE, PRE, POST) do { \
    bf16x8 afr[2][2]; \
    if ((p) == 0) { \
      _Pragma("unroll") for (int nf = 0; nf < 4; ++nf) { \
        bfr[nf][0] = *(const bf16x8*)&lds[(d) * 16384 + baseB + nf * 1024 + c0]; \
        bfr[nf][1] = *(const bf16x8*)&lds[(d) * 16384 + baseB + nf * 1024 + c1]; \
      } \
    } \
    _Pragma("unroll") for (int mfl = 0; mfl < 2; ++mfl) { \
      afr[mfl][0] = *(const bf16x8*)&lds[(d) * 16384 + (p) * 4096 + mfl * 1024 + baseA + c0]; \
      afr[mfl][1] = *(const bf16x8*)&lds[(d) * 16384 + (p) * 4096 + mfl * 1024 + baseA + c1]; \
    } \
    STAGE; \
    PRE; \
    __builtin_amdgcn_s_barrier(); \
    asm volatile("s_waitcnt lgkmcnt(0)" ::: "memory"); \
    __builtin_amdgcn_sched_barrier(0); \
    __builtin_amdgcn_s_setprio(1); \
    _Pragma("unroll") for (int mfl = 0; mfl < 2; ++mfl) \
      _Pragma("unroll") for (int nf = 0; nf < 4; ++nf) { \
        acc[(p) * 2 + mfl][nf] = __builtin_amdgcn_mfma_f32_16x16x32_bf16(afr[mfl][0], bfr[nf][0], acc[(p) * 2 + mfl][nf], 0, 0, 0); \
        acc[(p) * 2 + mfl][nf] = __builtin_amdgcn_mfma_f32_16x16x32_bf16(afr[mfl][1], bfr[nf][1], acc[(p) * 2 + mfl][nf], 0, 0, 0); \
      } \
    __builtin_amdgcn_s_setprio(0); \
    POST; \
    __builtin_amdgcn_s_barrier(); \
  } while (0)

template <int CBF16>
__global__ __launch_bounds__(512, 2) void gemm256(const u16* __restrict__ A,
                                                  const u16* __restrict__ B,
                                                  void* __restrict__ C,
                                                  int M, int Nn, int K) {
    __shared__ u16 lds[65536];   // A: [2][256][64] @0 ; B: same @32768 (128 KiB)
    const int tid = threadIdx.x;
    const int lane = tid & 63, wid = tid >> 6;
    const int wm = wid >> 2, wn = wid & 3;
    const int l15 = lane & 15, quad = lane >> 4;
    const int sw = l15 & 7;

    // XCD-aware bijective swizzle (gridDim.x % 8 == 0)
    int nbx = Nn >> 8;
    int cpx = gridDim.x >> 3;
    int wg = (blockIdx.x & 7) * cpx + (blockIdx.x >> 3);
    int m0 = (wg / nbx) << 8, n0 = (wg % nbx) << 8;

    // per-thread ds_read bases (u16 units) and swizzled chunk offsets
    const int baseA = wm * 2048 + l15 * 64;
    const int baseB = 32768 + wn * 4096 + l15 * 64;
    const int c0 = (quad ^ sw) * 8;
    const int c1 = ((4 + quad) ^ sw) * 8;
    const int dq = wid * 1024;                 // stage LDS base (j adds 512)

    // stage source pointers: LDS row ell -> global row, pre-swizzled col
    const u16 *pA00, *pA01, *pA10, *pA11, *pB00, *pB01, *pB10, *pB11;
    {
        int scol = ((lane & 7) ^ (lane >> 3)) * 8;
#define MKSRC(h, j, PA, PB) { \
        int ell = (h) * 128 + (wid * 2 + (j)) * 8 + (lane >> 3); \
        int g = ell >> 6, wmh = (ell >> 5) & 1, r = ell & 31; \
        PA = A + (size_t)(m0 + wmh * 128 + g * 32 + r) * K + scol; \
        PB = B + (size_t)(n0 + ell) * K + scol; }
        MKSRC(0, 0, pA00, pB00) MKSRC(0, 1, pA01, pB01)
        MKSRC(1, 0, pA10, pB10) MKSRC(1, 1, pA11, pB11)
#undef MKSRC
    }

    f32x4 acc[8][4];
    f32x4 zero4 = {0.f, 0.f, 0.f, 0.f};
#pragma unroll
    for (int i = 0; i < 8; ++i)
#pragma unroll
        for (int j = 0; j < 4; ++j) acc[i][j] = zero4;
    bf16x8 bfr[4][2];

    // prologue: tile0 (4 halves) -> buf0, tile1 (B0,B1,A0) -> buf1
    ST_B(0, 0, 0); ST_B(0, 1, 0); ST_A(0, 0, 0); ST_A(0, 1, 0);
    ST_B(1, 0, 1); ST_B(1, 1, 1); ST_A(1, 0, 1);
    VM6;                                   // tile0 landed; 3 halves in flight
    __builtin_amdgcn_s_barrier();

    const int NIT = (K >> 7) - 1;          // T/2 - 1 iterations
    for (int i = 0; i < NIT; ++i) {
        int t = 2 * i;
        PHASE(0, 0, ST_A(1, 1, t + 1), LGK8, NOPS);
        PHASE(0, 1, ST_B(0, 0, t + 2), NOPS, NOPS);
        PHASE(0, 2, ST_B(0, 1, t + 2), NOPS, NOPS);
        PHASE(0, 3, ST_A(0, 0, t + 2), NOPS, VM6);
        PHASE(1, 0, ST_A(0, 1, t + 2), LGK8, NOPS);
        PHASE(1, 1, ST_B(1, 0, t + 3), NOPS, NOPS);
        PHASE(1, 2, ST_B(1, 1, t + 3), NOPS, NOPS);
        PHASE(1, 3, ST_A(1, 0, t + 3), NOPS, VM6);
    }
    {   // epilogue: tiles T-2 (buf0), T-1 (buf1); only (T-1).A1 left to stage
        int T = K >> 6;
        PHASE(0, 0, ST_A(1, 1, T - 1), LGK8, NOPS);
        PHASE(0, 1, NOPS, NOPS, NOPS);
        PHASE(0, 2, NOPS, NOPS, NOPS);
        PHASE(0, 3, NOPS, NOPS, VM0);
        PHASE(1, 0, NOPS, LGK8, NOPS);
        PHASE(1, 1, NOPS, NOPS, NOPS);
        PHASE(1, 2, NOPS, NOPS, NOPS);
        PHASE(1, 3, NOPS, NOPS, NOPS);
    }

    // C write: rr = m0 + wm*128 + mf*16 + quad*4 + r ; cc = n0 + wn*64 + nf*16 + l15
#pragma unroll
    for (int mf = 0; mf < 8; ++mf)
#pragma unroll
        for (int nf = 0; nf < 4; ++nf)
#pragma unroll
            for (int r = 0; r < 4; ++r) {
                int rr = m0 + wm * 128 + mf * 16 + quad * 4 + r;
                int cc = n0 + wn * 64 + nf * 16 + l15;
                if (CBF16)
                    ((u16*)C)[(size_t)rr * Nn + cc] = f2bf(acc[mf][nf][r]);
                else
                    ((float*)C)[(size_t)rr * Nn + cc] = acc[mf][nf][r];
            }
}

// ---------------- RoPE on q,k + reshape to [H,N,DH] ----------------
// Q is pre-scaled by (1/8)*log2(e) so flash's exp2 needs no multiply.
__global__ __launch_bounds__(256) void rope_qk(const u16* __restrict__ qkv,
                                               const float* __restrict__ pe,
                                               u16* __restrict__ Qr,
                                               u16* __restrict__ Kr) {
    int n = blockIdx.x;
    int tid = threadIdx.x;
    const u16* qrow = qkv + (size_t)n * DMODEL;
    const float4* pen = (const float4*)(pe + (size_t)n * 128);
#pragma unroll
    for (int it = 0; it < 2; ++it) {
        int p = it * 256 + tid;      // pair index 0..511
        int h = p >> 5, i = p & 31;
        float4 w = pen[i];
        size_t obase = ((size_t)h * N_TOK + n) * DHEAD + 2 * i;
        unsigned qq = *(const unsigned*)&qrow[h * 64 + 2 * i];
        float q0 = bf2f((u16)qq), q1 = bf2f((u16)(qq >> 16));
        *(unsigned*)&Qr[obase] = pk2bf((w.x * q0 + w.y * q1) * SCALE_LOG2E,
                                       (w.z * q0 + w.w * q1) * SCALE_LOG2E);
        unsigned kk = *(const unsigned*)&qrow[INNER + h * 64 + 2 * i];
        float k0 = bf2f((u16)kk), k1 = bf2f((u16)(kk >> 16));
        *(unsigned*)&Kr[obase] = pk2bf(w.x * k0 + w.y * k1, w.z * k0 + w.w * k1);
    }
}

// ---------------- V transpose: Vt[h][d][n] = qkv[n][2048 + h*64 + d] ------
__global__ __launch_bounds__(256) void v_transpose(const u16* __restrict__ qkv,
                                                   u16* __restrict__ Vt) {
    __shared__ u16 t[64][65];
    int n0 = blockIdx.x * 64;
    int h = blockIdx.y;
    int tid = threadIdx.x;
#pragma unroll
    for (int it = 0; it < 4; ++it) {
        int nr = it * 16 + (tid >> 4);
        int dc = (tid & 15) * 4;
        ushort4 v = *(const ushort4*)&qkv[(size_t)(n0 + nr) * DMODEL + 2 * INNER + h * 64 + dc];
        t[dc + 0][nr] = v.x; t[dc + 1][nr] = v.y; t[dc + 2][nr] = v.z; t[dc + 3][nr] = v.w;
    }
    __syncthreads();
#pragma unroll
    for (int it = 0; it < 4; ++it) {
        int dr = it * 16 + (tid >> 4);
        int nc = (tid & 15) * 4;
        ushort4 v;
        v.x = t[dr][nc]; v.y = t[dr][nc + 1]; v.z = t[dr][nc + 2]; v.w = t[dr][nc + 3];
        *(ushort4*)&Vt[((size_t)h * 64 + dr) * N_TOK + n0 + nc] = v;
    }
}

// ---------------- Flash attention (fixed-bias softmax, no online max) -----
// grid (32 qtiles, 16 heads); 256 thr = 4 waves; wave owns 32 q-rows.
// Q pre-scaled so S^T (bf16 MFMA) is directly the exp2 argument.
// p = exp2(s) raw, carried in BF16 (range 2^127 — raw p can reach ~2^30,
// which overflows f16; f16 attempt failed R5). l via ones-row MFMA.
__global__ __launch_bounds__(256, 2) void flash_attn(const u16* __restrict__ Q,
                                                     const u16* __restrict__ K,
                                                     const u16* __restrict__ Vt,
                                                     u16* __restrict__ O) {
    __shared__ u16 lds_all[16384];           // 32 KB
    u16* Ks = lds_all;                       // [key 64][chunk 8][8]  (8 KB) bf16
    u16* Vs = lds_all + 4096;                // [d 64][chunk 8][8]    (8 KB) bf16
    int tid = threadIdx.x, lane = tid & 63, wid = tid >> 6;
    u16* Ps = lds_all + 8192 + wid * 2048;   // per-wave [q 32][chunk 8][8] (4 KB) bf16
    int l15 = lane & 15, quad = lane >> 4;
    int sw = l15 & 7;
    int h = blockIdx.y;
    int q0 = blockIdx.x * 128 + wid * 32;
    const u16* Qh = Q + (size_t)h * N_TOK * DHEAD;
    const u16* Kh = K + (size_t)h * N_TOK * DHEAD;
    const u16* Vh = Vt + (size_t)h * DHEAD * N_TOK;

    f32x4 zero4 = {0.f, 0.f, 0.f, 0.f};
    bf16x8 ones;
#pragma unroll
    for (int i = 0; i < 8; ++i) ones[i] = (short)0x3F80;  // bf16 1.0

    // Q fragments (B operand): B[n=q=l15][k=dhead]
    bf16x8 aq[2][2];
#pragma unroll
    for (int mtQ = 0; mtQ < 2; ++mtQ)
#pragma unroll
        for (int kc = 0; kc < 2; ++kc)
            aq[mtQ][kc] = *(const bf16x8*)&Qh[(size_t)(q0 + mtQ * 16 + l15) * DHEAD + kc * 32 + quad * 8];

    f32x4 o[2][4], lacc[2];
#pragma unroll
    for (int mtQ = 0; mtQ < 2; ++mtQ) {
#pragma unroll
        for (int dt = 0; dt < 4; ++dt) o[mtQ][dt] = zero4;
        lacc[mtQ] = zero4;
    }

    // staging: wave stages rows [wid*16, wid*16+16); XOR swizzle on global col
    int rbase = wid * 16;
    int rowoff = lane >> 3;                      // 0..7
    int csw = ((lane & 7) ^ rowoff) * 8;         // swizzled source column (u16)

    for (int kt = 0; kt < N_TOK; kt += 64) {
        load_lds16(&Kh[(size_t)(kt + rbase + rowoff) * DHEAD + csw], &Ks[rbase * 64]);
        load_lds16(&Kh[(size_t)(kt + rbase + 8 + rowoff) * DHEAD + csw], &Ks[(rbase + 8) * 64]);
        load_lds16(&Vh[(size_t)(rbase + rowoff) * N_TOK + kt + csw], &Vs[rbase * 64]);
        load_lds16(&Vh[(size_t)(rbase + 8 + rowoff) * N_TOK + kt + csw], &Vs[(rbase + 8) * 64]);
        __syncthreads();

        bf16x8 bk[4][2], av[4][2];
#pragma unroll
        for (int t = 0; t < 4; ++t)
#pragma unroll
            for (int kc = 0; kc < 2; ++kc) {
                int off = (t * 16 + l15) * 64 + (((kc * 4 + quad) ^ sw) * 8);
                bk[t][kc] = *(const bf16x8*)&Ks[off];
                av[t][kc] = *(const bf16x8*)&Vs[off];
            }
        __syncthreads();

#pragma unroll
        for (int mtQ = 0; mtQ < 2; ++mtQ) {
            // S^T: rows=key, cols=q (already in log2-exp domain via Q pre-scale)
            f32x4 s[4];
#pragma unroll
            for (int ntK = 0; ntK < 4; ++ntK) {
                f32x4 t0 = __builtin_amdgcn_mfma_f32_16x16x32_bf16(bk[ntK][0], aq[mtQ][0], zero4, 0, 0, 0);
                s[ntK] = __builtin_amdgcn_mfma_f32_16x16x32_bf16(bk[ntK][1], aq[mtQ][1], t0, 0, 0, 0);
            }
            // p = exp2(s); pack to bf16 and store P^T (swizzled chunks)
#pragma unroll
            for (int ntK = 0; ntK < 4; ++ntK) {
                uint2 pv;
                pv.x = pk2bf(__builtin_amdgcn_exp2f(s[ntK][0]), __builtin_amdgcn_exp2f(s[ntK][1]));
                pv.y = pk2bf(__builtin_amdgcn_exp2f(s[ntK][2]), __builtin_amdgcn_exp2f(s[ntK][3]));
                int pc = (ntK * 2 + (quad >> 1)) ^ sw;
                *(uint2*)&Ps[(mtQ * 16 + l15) * 64 + pc * 8 + (quad & 1) * 4] = pv;
            }
            // reload as B operand: B[n=q=l15][k=key]
            bf16x8 bp0 = *(const bf16x8*)&Ps[(mtQ * 16 + l15) * 64 + ((quad ^ sw) * 8)];
            bf16x8 bp1 = *(const bf16x8*)&Ps[(mtQ * 16 + l15) * 64 + (((4 + quad) ^ sw) * 8)];
            // l += sum_k P (ones-row MFMA; every lane gets l(q) in all 4 elems)
            lacc[mtQ] = __builtin_amdgcn_mfma_f32_16x16x32_bf16(ones, bp0, lacc[mtQ], 0, 0, 0);
            lacc[mtQ] = __builtin_amdgcn_mfma_f32_16x16x32_bf16(ones, bp1, lacc[mtQ], 0, 0, 0);
#pragma unroll
            for (int dt = 0; dt < 4; ++dt) {
                o[mtQ][dt] = __builtin_amdgcn_mfma_f32_16x16x32_bf16(av[dt][0], bp0, o[mtQ][dt], 0, 0, 0);
                o[mtQ][dt] = __builtin_amdgcn_mfma_f32_16x16x32_bf16(av[dt][1], bp1, o[mtQ][dt], 0, 0, 0);
            }
        }
    }

    // epilogue: transpose O^T -> O via per-wave LDS scratch, then coalesced write
    __syncthreads();
    u16* scratch = lds_all + wid * 2048;     // [q 32][d 64]
#pragma unroll
    for (int mtQ = 0; mtQ < 2; ++mtQ) {
        float rl = 1.f / lacc[mtQ][0];
#pragma unroll
        for (int dt = 0; dt < 4; ++dt) {
            uint2 ov;
            ov.x = pk2bf(o[mtQ][dt][0] * rl, o[mtQ][dt][1] * rl);
            ov.y = pk2bf(o[mtQ][dt][2] * rl, o[mtQ][dt][3] * rl);
            *(uint2*)&scratch[(mtQ * 16 + l15) * 64 + dt * 16 + quad * 4] = ov;
        }
    }
#pragma unroll
    for (int p = 0; p < 4; ++p) {
        int q_local = p * 8 + (lane >> 3);
        int dcol = (lane & 7) * 8;
        bf16x8 v = *(const bf16x8*)&scratch[q_local * 64 + dcol];
        *(bf16x8*)&O[(size_t)(q0 + q_local) * INNER + h * 64 + dcol] = v;
    }
}

extern "C" void kernel_launch(void* const* d_in, const int* in_sizes, int n_in,
                              void* d_out, int out_size, void* d_ws, size_t ws_size,
                              hipStream_t stream) {
    const float* x     = (const float*)d_in[0];
    const float* pe    = (const float*)d_in[1];
    const float* w_qkv = (const float*)d_in[2];
    const float* w_out = (const float*)d_in[3];
    const float* ln_g  = (const float*)d_in[4];
    const float* ln_b  = (const float*)d_in[5];
    float* out = (float*)d_out;

    char* ws = (char*)d_ws;
    u16* xn  = (u16*)ws;  ws += (size_t)N_TOK * DMODEL * 2;
    u16* wq  = (u16*)ws;  ws += (size_t)3 * INNER * DMODEL * 2;
    u16* wo  = (u16*)ws;  ws += (size_t)DMODEL * INNER * 2;
    u16* qkv = (u16*)ws;  ws += (size_t)N_TOK * DMODEL * 2;
    u16* Qr  = (u16*)ws;  ws += (size_t)NH * N_TOK * DHEAD * 2;
    u16* Kr  = (u16*)ws;  ws += (size_t)NH * N_TOK * DHEAD * 2;
    u16* Vt  = (u16*)ws;  ws += (size_t)NH * DHEAD * N_TOK * 2;
    u16* Ob  = (u16*)ws;  ws += (size_t)N_TOK * INNER * 2;

    ln_kernel<<<N_TOK, 256, 0, stream>>>(x, ln_g, ln_b, xn);
    {
        int n4 = 3 * INNER * DMODEL / 4;
        cvt_bf16<<<(n4 + 255) / 256, 256, 0, stream>>>(w_qkv, wq, n4);
    }
    {
        int n4 = DMODEL * INNER / 4;
        cvt_bf16<<<(n4 + 255) / 256, 256, 0, stream>>>(w_out, wo, n4);
    }
    gemm256<1><<<dim3((N_TOK / 256) * (DMODEL / 256)), 512, 0, stream>>>(xn, wq, qkv, N_TOK, DMODEL, DMODEL);
    rope_qk<<<N_TOK, 256, 0, stream>>>(qkv, pe, Qr, Kr);
    v_transpose<<<dim3(N_TOK / 64, NH), 256, 0, stream>>>(qkv, Vt);
    flash_attn<<<dim3(N_TOK / 128, NH), 256, 0, stream>>>(Qr, Kr, Vt, Ob);
    gemm256<0><<<dim3((N_TOK / 256) * (DMODEL / 256)), 512, 0, stream>>>(Ob, wo, out, N_TOK, DMODEL, INNER);
}

// Round 3
// 361.607 us; speedup vs baseline: 1.1131x; 1.0380x over previous
//
#include <hip/hip_runtime.h>
#include <hip/hip_bf16.h>

typedef unsigned short u16;
typedef __attribute__((ext_vector_type(8))) short bf16x8;
typedef __attribute__((ext_vector_type(4))) float f32x4;

#define N_TOK 4096
#define DMODEL 3072
#define NH 16
#define DHEAD 64
#define INNER 1024
#define SCALE_LOG2E 0.18033688011112042f  /* (1/8) * log2(e) */

__device__ __forceinline__ u16 f2bf(float f) {
    union { float f; unsigned u; } un; un.f = f;
    unsigned r = un.u + 0x7fffu + ((un.u >> 16) & 1u);
    return (u16)(r >> 16);
}
__device__ __forceinline__ float bf2f(u16 u) {
    union { unsigned u; float f; } x; x.u = ((unsigned)u) << 16; return x.f;
}
// pack two f32 -> two bf16 (round-half-up) in 3 VALU ops; a -> low 16
__device__ __forceinline__ unsigned pk2bf(float a, float b) {
    union { float f; unsigned u; } ua, ub; ua.f = a; ub.f = b;
    return __builtin_amdgcn_perm(ub.u + 0x8000u, ua.u + 0x8000u, 0x07060302u);
}
__device__ __forceinline__ void load_lds16(const u16* g, u16* l) {
    __builtin_amdgcn_global_load_lds(
        (const __attribute__((address_space(1))) unsigned int*)g,
        (__attribute__((address_space(3))) unsigned int*)l, 16, 0, 0);
}

// ---------------- LayerNorm: x f32 [4096,3072] -> xn bf16 ----------------
__global__ __launch_bounds__(256) void ln_kernel(const float* __restrict__ x,
                                                 const float* __restrict__ g,
                                                 const float* __restrict__ b,
                                                 u16* __restrict__ xn) {
    int row = blockIdx.x;
    int tid = threadIdx.x;
    const float4* xr = (const float4*)(x + (size_t)row * DMODEL);
    float4 v[3];
    float s = 0.f, ss = 0.f;
#pragma unroll
    for (int i = 0; i < 3; ++i) {
        v[i] = xr[i * 256 + tid];
        s  += v[i].x + v[i].y + v[i].z + v[i].w;
        ss += v[i].x * v[i].x + v[i].y * v[i].y + v[i].z * v[i].z + v[i].w * v[i].w;
    }
#pragma unroll
    for (int off = 32; off; off >>= 1) {
        s  += __shfl_xor(s, off);
        ss += __shfl_xor(ss, off);
    }
    __shared__ float red[8];
    int wid = tid >> 6, lane = tid & 63;
    if (lane == 0) { red[wid] = s; red[wid + 4] = ss; }
    __syncthreads();
    s  = red[0] + red[1] + red[2] + red[3];
    ss = red[4] + red[5] + red[6] + red[7];
    float mean = s * (1.f / DMODEL);
    float var  = ss * (1.f / DMODEL) - mean * mean;
    float rstd = rsqrtf(var + 1e-5f);
    ushort4* orow = (ushort4*)(xn + (size_t)row * DMODEL);
#pragma unroll
    for (int i = 0; i < 3; ++i) {
        float4 gg = ((const float4*)g)[i * 256 + tid];
        float4 bb = ((const float4*)b)[i * 256 + tid];
        ushort4 o;
        o.x = f2bf((v[i].x - mean) * rstd * gg.x + bb.x);
        o.y = f2bf((v[i].y - mean) * rstd * gg.y + bb.y);
        o.z = f2bf((v[i].z - mean) * rstd * gg.z + bb.z);
        o.w = f2bf((v[i].w - mean) * rstd * gg.w + bb.w);
        orow[i * 256 + tid] = o;
    }
}

// ---------------- f32 -> bf16 convert ----------------
__global__ __launch_bounds__(256) void cvt_bf16(const float* __restrict__ in,
                                                u16* __restrict__ out, int n4) {
    int i = blockIdx.x * 256 + threadIdx.x;
    if (i < n4) {
        float4 v = ((const float4*)in)[i];
        ushort4 o;
        o.x = f2bf(v.x); o.y = f2bf(v.y); o.z = f2bf(v.z); o.w = f2bf(v.w);
        ((ushort4*)out)[i] = o;
    }
}

// ============ GEMM 256x256 8-phase (T2+T3+T4+T5), C = A * B^T ============
// (unchanged from R2 — verified; MfmaUtil up, both gemms now < flash_attn)

#define VM6 asm volatile("s_waitcnt vmcnt(6)" ::: "memory")
#define VM4 asm volatile("s_waitcnt vmcnt(4)" ::: "memory")
#define VM0 asm volatile("s_waitcnt vmcnt(0)" ::: "memory")
#define LGK8 asm volatile("s_waitcnt lgkmcnt(8)" ::: "memory")
#define NOPS ((void)0)

#define ST_A(d, h, t) do { \
    load_lds16(pA##h##0 + (size_t)(t) * 64, &lds[(d) * 16384 + (h) * 8192 + dq]); \
    load_lds16(pA##h##1 + (size_t)(t) * 64, &lds[(d) * 16384 + (h) * 8192 + dq + 512]); \
  } while (0)
#define ST_B(d, h, t) do { \
    load_lds16(pB##h##0 + (size_t)(t) * 64, &lds[32768 + (d) * 16384 + (h) * 8192 + dq]); \
    load_lds16(pB##h##1 + (size_t)(t) * 64, &lds[32768 + (d) * 16384 + (h) * 8192 + dq + 512]); \
  } while (0)

#define PHASE(d, p, STAGE, PRE, POST) do { \
    bf16x8 afr[2][2]; \
    if ((p) == 0) { \
      _Pragma("unroll") for (int nf = 0; nf < 4; ++nf) { \
        bfr[nf][0] = *(const bf16x8*)&lds[(d) * 16384 + baseB + nf * 1024 + c0]; \
        bfr[nf][1] = *(const bf16x8*)&lds[(d) * 16384 + baseB + nf * 1024 + c1]; \
      } \
    } \
    _Pragma("unroll") for (int mfl = 0; mfl < 2; ++mfl) { \
      afr[mfl][0] = *(const bf16x8*)&lds[(d) * 16384 + (p) * 4096 + mfl * 1024 + baseA + c0]; \
      afr[mfl][1] = *(const bf16x8*)&lds[(d) * 16384 + (p) * 4096 + mfl * 1024 + baseA + c1]; \
    } \
    STAGE; \
    PRE; \
    __builtin_amdgcn_s_barrier(); \
    asm volatile("s_waitcnt lgkmcnt(0)" ::: "memory"); \
    __builtin_amdgcn_sched_barrier(0); \
    __builtin_amdgcn_s_setprio(1); \
    _Pragma("unroll") for (int mfl = 0; mfl < 2; ++mfl) \
      _Pragma("unroll") for (int nf = 0; nf < 4; ++nf) { \
        acc[(p) * 2 + mfl][nf] = __builtin_amdgcn_mfma_f32_16x16x32_bf16(afr[mfl][0], bfr[nf][0], acc[(p) * 2 + mfl][nf], 0, 0, 0); \
        acc[(p) * 2 + mfl][nf] = __builtin_amdgcn_mfma_f32_16x16x32_bf16(afr[mfl][1], bfr[nf][1], acc[(p) * 2 + mfl][nf], 0, 0, 0); \
      } \
    __builtin_amdgcn_s_setprio(0); \
    POST; \
    __builtin_amdgcn_s_barrier(); \
  } while (0)

template <int CBF16>
__global__ __launch_bounds__(512, 2) void gemm256(const u16* __restrict__ A,
                                                  const u16* __restrict__ B,
                                                  void* __restrict__ C,
                                                  int M, int Nn, int K) {
    __shared__ u16 lds[65536];   // A: [2][256][64] @0 ; B: same @32768 (128 KiB)
    const int tid = threadIdx.x;
    const int lane = tid & 63, wid = tid >> 6;
    const int wm = wid >> 2, wn = wid & 3;
    const int l15 = lane & 15, quad = lane >> 4;
    const int sw = l15 & 7;

    // XCD-aware bijective swizzle (gridDim.x % 8 == 0)
    int nbx = Nn >> 8;
    int cpx = gridDim.x >> 3;
    int wg = (blockIdx.x & 7) * cpx + (blockIdx.x >> 3);
    int m0 = (wg / nbx) << 8, n0 = (wg % nbx) << 8;

    // per-thread ds_read bases (u16 units) and swizzled chunk offsets
    const int baseA = wm * 2048 + l15 * 64;
    const int baseB = 32768 + wn * 4096 + l15 * 64;
    const int c0 = (quad ^ sw) * 8;
    const int c1 = ((4 + quad) ^ sw) * 8;
    const int dq = wid * 1024;                 // stage LDS base (j adds 512)

    // stage source pointers: LDS row ell -> global row, pre-swizzled col
    const u16 *pA00, *pA01, *pA10, *pA11, *pB00, *pB01, *pB10, *pB11;
    {
        int scol = ((lane & 7) ^ (lane >> 3)) * 8;
#define MKSRC(h, j, PA, PB) { \
        int ell = (h) * 128 + (wid * 2 + (j)) * 8 + (lane >> 3); \
        int g = ell >> 6, wmh = (ell >> 5) & 1, r = ell & 31; \
        PA = A + (size_t)(m0 + wmh * 128 + g * 32 + r) * K + scol; \
        PB = B + (size_t)(n0 + ell) * K + scol; }
        MKSRC(0, 0, pA00, pB00) MKSRC(0, 1, pA01, pB01)
        MKSRC(1, 0, pA10, pB10) MKSRC(1, 1, pA11, pB11)
#undef MKSRC
    }

    f32x4 acc[8][4];
    f32x4 zero4 = {0.f, 0.f, 0.f, 0.f};
#pragma unroll
    for (int i = 0; i < 8; ++i)
#pragma unroll
        for (int j = 0; j < 4; ++j) acc[i][j] = zero4;
    bf16x8 bfr[4][2];

    // prologue: tile0 (4 halves) -> buf0, tile1 (B0,B1,A0) -> buf1
    ST_B(0, 0, 0); ST_B(0, 1, 0); ST_A(0, 0, 0); ST_A(0, 1, 0);
    ST_B(1, 0, 1); ST_B(1, 1, 1); ST_A(1, 0, 1);
    VM6;                                   // tile0 landed; 3 halves in flight
    __builtin_amdgcn_s_barrier();

    const int NIT = (K >> 7) - 1;          // T/2 - 1 iterations
    for (int i = 0; i < NIT; ++i) {
        int t = 2 * i;
        PHASE(0, 0, ST_A(1, 1, t + 1), LGK8, NOPS);
        PHASE(0, 1, ST_B(0, 0, t + 2), NOPS, NOPS);
        PHASE(0, 2, ST_B(0, 1, t + 2), NOPS, NOPS);
        PHASE(0, 3, ST_A(0, 0, t + 2), NOPS, VM6);
        PHASE(1, 0, ST_A(0, 1, t + 2), LGK8, NOPS);
        PHASE(1, 1, ST_B(1, 0, t + 3), NOPS, NOPS);
        PHASE(1, 2, ST_B(1, 1, t + 3), NOPS, NOPS);
        PHASE(1, 3, ST_A(1, 0, t + 3), NOPS, VM6);
    }
    {   // epilogue: tiles T-2 (buf0), T-1 (buf1); only (T-1).A1 left to stage
        int T = K >> 6;
        PHASE(0, 0, ST_A(1, 1, T - 1), LGK8, NOPS);
        PHASE(0, 1, NOPS, NOPS, NOPS);
        PHASE(0, 2, NOPS, NOPS, NOPS);
        PHASE(0, 3, NOPS, NOPS, VM0);
        PHASE(1, 0, NOPS, LGK8, NOPS);
        PHASE(1, 1, NOPS, NOPS, NOPS);
        PHASE(1, 2, NOPS, NOPS, NOPS);
        PHASE(1, 3, NOPS, NOPS, NOPS);
    }

    // C write: rr = m0 + wm*128 + mf*16 + quad*4 + r ; cc = n0 + wn*64 + nf*16 + l15
#pragma unroll
    for (int mf = 0; mf < 8; ++mf)
#pragma unroll
        for (int nf = 0; nf < 4; ++nf)
#pragma unroll
            for (int r = 0; r < 4; ++r) {
                int rr = m0 + wm * 128 + mf * 16 + quad * 4 + r;
                int cc = n0 + wn * 64 + nf * 16 + l15;
                if (CBF16)
                    ((u16*)C)[(size_t)rr * Nn + cc] = f2bf(acc[mf][nf][r]);
                else
                    ((float*)C)[(size_t)rr * Nn + cc] = acc[mf][nf][r];
            }
}

// ---------------- RoPE on q,k + reshape to [H,N,DH] ----------------
// Q is pre-scaled by (1/8)*log2(e) so flash's exp2 needs no multiply.
__global__ __launch_bounds__(256) void rope_qk(const u16* __restrict__ qkv,
                                               const float* __restrict__ pe,
                                               u16* __restrict__ Qr,
                                               u16* __restrict__ Kr) {
    int n = blockIdx.x;
    int tid = threadIdx.x;
    const u16* qrow = qkv + (size_t)n * DMODEL;
    const float4* pen = (const float4*)(pe + (size_t)n * 128);
#pragma unroll
    for (int it = 0; it < 2; ++it) {
        int p = it * 256 + tid;      // pair index 0..511
        int h = p >> 5, i = p & 31;
        float4 w = pen[i];
        size_t obase = ((size_t)h * N_TOK + n) * DHEAD + 2 * i;
        unsigned qq = *(const unsigned*)&qrow[h * 64 + 2 * i];
        float q0 = bf2f((u16)qq), q1 = bf2f((u16)(qq >> 16));
        *(unsigned*)&Qr[obase] = pk2bf((w.x * q0 + w.y * q1) * SCALE_LOG2E,
                                       (w.z * q0 + w.w * q1) * SCALE_LOG2E);
        unsigned kk = *(const unsigned*)&qrow[INNER + h * 64 + 2 * i];
        float k0 = bf2f((u16)kk), k1 = bf2f((u16)(kk >> 16));
        *(unsigned*)&Kr[obase] = pk2bf(w.x * k0 + w.y * k1, w.z * k0 + w.w * k1);
    }
}

// ---------------- V transpose: Vt[h][d][n] = qkv[n][2048 + h*64 + d] ------
__global__ __launch_bounds__(256) void v_transpose(const u16* __restrict__ qkv,
                                                   u16* __restrict__ Vt) {
    __shared__ u16 t[64][65];
    int n0 = blockIdx.x * 64;
    int h = blockIdx.y;
    int tid = threadIdx.x;
#pragma unroll
    for (int it = 0; it < 4; ++it) {
        int nr = it * 16 + (tid >> 4);
        int dc = (tid & 15) * 4;
        ushort4 v = *(const ushort4*)&qkv[(size_t)(n0 + nr) * DMODEL + 2 * INNER + h * 64 + dc];
        t[dc + 0][nr] = v.x; t[dc + 1][nr] = v.y; t[dc + 2][nr] = v.z; t[dc + 3][nr] = v.w;
    }
    __syncthreads();
#pragma unroll
    for (int it = 0; it < 4; ++it) {
        int dr = it * 16 + (tid >> 4);
        int nc = (tid & 15) * 4;
        ushort4 v;
        v.x = t[dr][nc]; v.y = t[dr][nc + 1]; v.z = t[dr][nc + 2]; v.w = t[dr][nc + 3];
        *(ushort4*)&Vt[((size_t)h * 64 + dr) * N_TOK + n0 + nc] = v;
    }
}

// ---------------- Flash attention: 2-deep pipelined K/V staging -----------
// grid (32 qtiles, 16 heads); 256 thr = 4 waves; wave owns 32 q-rows.
// T3+T4: K/V double-buffered (2x16KB), counted vmcnt(4) — never drain-0 in
// steady state. Per tile: ds_read(buf cur) -> lgkm0 -> bar -> stage(t+2 into
// buf cur) -> compute -> vmcnt(4) -> bar. Tail peeled (t=62 VM0, t=63 none).
// Race audit: overwrite of buf[cur] issued only after barrier that follows
// all waves' completed reads; reads of buf[cur^1] only after all waves'
// vmcnt(4)+barrier (covers cross-wave staged rows).

#define FA_STAGE(d, kt) do { \
    load_lds16(&Kh[(size_t)((kt) + rbase + rowoff) * DHEAD + csw], &lds_all[(d) * 8192 + rbase * 64]); \
    load_lds16(&Kh[(size_t)((kt) + rbase + 8 + rowoff) * DHEAD + csw], &lds_all[(d) * 8192 + (rbase + 8) * 64]); \
    load_lds16(&Vh[(size_t)(rbase + rowoff) * N_TOK + (kt) + csw], &lds_all[(d) * 8192 + 4096 + rbase * 64]); \
    load_lds16(&Vh[(size_t)(rbase + 8 + rowoff) * N_TOK + (kt) + csw], &lds_all[(d) * 8192 + 4096 + (rbase + 8) * 64]); \
  } while (0)

#define FA_TILE(d, STAGE_STMT, WAIT_STMT) do { \
    bf16x8 bk[4][2], av[4][2]; \
    _Pragma("unroll") for (int tt = 0; tt < 4; ++tt) \
      _Pragma("unroll") for (int kc = 0; kc < 2; ++kc) { \
        int off = (d) * 8192 + (tt * 16 + l15) * 64 + (((kc * 4 + quad) ^ sw) * 8); \
        bk[tt][kc] = *(const bf16x8*)&lds_all[off]; \
        av[tt][kc] = *(const bf16x8*)&lds_all[off + 4096]; \
      } \
    asm volatile("s_waitcnt lgkmcnt(0)" ::: "memory"); \
    __builtin_amdgcn_sched_barrier(0); \
    __builtin_amdgcn_s_barrier(); \
    __builtin_amdgcn_sched_barrier(0); \
    STAGE_STMT; \
    _Pragma("unroll") for (int mtQ = 0; mtQ < 2; ++mtQ) { \
      f32x4 s[4]; \
      _Pragma("unroll") for (int ntK = 0; ntK < 4; ++ntK) { \
        f32x4 t0 = __builtin_amdgcn_mfma_f32_16x16x32_bf16(bk[ntK][0], aq[mtQ][0], zero4, 0, 0, 0); \
        s[ntK] = __builtin_amdgcn_mfma_f32_16x16x32_bf16(bk[ntK][1], aq[mtQ][1], t0, 0, 0, 0); \
      } \
      _Pragma("unroll") for (int ntK = 0; ntK < 4; ++ntK) { \
        uint2 pv; \
        pv.x = pk2bf(__builtin_amdgcn_exp2f(s[ntK][0]), __builtin_amdgcn_exp2f(s[ntK][1])); \
        pv.y = pk2bf(__builtin_amdgcn_exp2f(s[ntK][2]), __builtin_amdgcn_exp2f(s[ntK][3])); \
        int pc = (ntK * 2 + (quad >> 1)) ^ sw; \
        *(uint2*)&Ps[(mtQ * 16 + l15) * 64 + pc * 8 + (quad & 1) * 4] = pv; \
      } \
      bf16x8 bp0 = *(const bf16x8*)&Ps[(mtQ * 16 + l15) * 64 + ((quad ^ sw) * 8)]; \
      bf16x8 bp1 = *(const bf16x8*)&Ps[(mtQ * 16 + l15) * 64 + (((4 + quad) ^ sw) * 8)]; \
      lacc[mtQ] = __builtin_amdgcn_mfma_f32_16x16x32_bf16(ones, bp0, lacc[mtQ], 0, 0, 0); \
      lacc[mtQ] = __builtin_amdgcn_mfma_f32_16x16x32_bf16(ones, bp1, lacc[mtQ], 0, 0, 0); \
      _Pragma("unroll") for (int dt = 0; dt < 4; ++dt) { \
        o[mtQ][dt] = __builtin_amdgcn_mfma_f32_16x16x32_bf16(av[dt][0], bp0, o[mtQ][dt], 0, 0, 0); \
        o[mtQ][dt] = __builtin_amdgcn_mfma_f32_16x16x32_bf16(av[dt][1], bp1, o[mtQ][dt], 0, 0, 0); \
      } \
    } \
    WAIT_STMT; \
    __builtin_amdgcn_s_barrier(); \
    __builtin_amdgcn_sched_barrier(0); \
  } while (0)

__global__ __launch_bounds__(256, 2) void flash_attn(const u16* __restrict__ Q,
                                                     const u16* __restrict__ K,
                                                     const u16* __restrict__ Vt,
                                                     u16* __restrict__ O) {
    __shared__ u16 lds_all[24576];           // 48 KB: KV dbuf 2x16KB + Ps 16KB
    int tid = threadIdx.x, lane = tid & 63, wid = tid >> 6;
    u16* Ps = lds_all + 16384 + wid * 2048;  // per-wave [q 32][chunk 8][8] (4 KB)
    int l15 = lane & 15, quad = lane >> 4;
    int sw = l15 & 7;
    int h = blockIdx.y;
    int q0 = blockIdx.x * 128 + wid * 32;
    const u16* Qh = Q + (size_t)h * N_TOK * DHEAD;
    const u16* Kh = K + (size_t)h * N_TOK * DHEAD;
    const u16* Vh = Vt + (size_t)h * DHEAD * N_TOK;

    f32x4 zero4 = {0.f, 0.f, 0.f, 0.f};
    bf16x8 ones;
#pragma unroll
    for (int i = 0; i < 8; ++i) ones[i] = (short)0x3F80;  // bf16 1.0

    // Q fragments (B operand): B[n=q=l15][k=dhead]
    bf16x8 aq[2][2];
#pragma unroll
    for (int mtQ = 0; mtQ < 2; ++mtQ)
#pragma unroll
        for (int kc = 0; kc < 2; ++kc)
            aq[mtQ][kc] = *(const bf16x8*)&Qh[(size_t)(q0 + mtQ * 16 + l15) * DHEAD + kc * 32 + quad * 8];

    f32x4 o[2][4], lacc[2];
#pragma unroll
    for (int mtQ = 0; mtQ < 2; ++mtQ) {
#pragma unroll
        for (int dt = 0; dt < 4; ++dt) o[mtQ][dt] = zero4;
        lacc[mtQ] = zero4;
    }

    // staging: wave stages rows [wid*16, wid*16+16); XOR swizzle on global col
    int rbase = wid * 16;
    int rowoff = lane >> 3;                      // 0..7
    int csw = ((lane & 7) ^ rowoff) * 8;         // swizzled source column (u16)

    // prologue: tiles 0,1 -> bufs 0,1 (8 loads); wait tile0 (4 newest remain)
    FA_STAGE(0, 0);
    FA_STAGE(1, 64);
    VM4;
    __builtin_amdgcn_s_barrier();
    __builtin_amdgcn_sched_barrier(0);

    for (int t = 0; t < 62; t += 2) {
        FA_TILE(0, FA_STAGE(0, (t + 2) * 64), VM4);
        FA_TILE(1, FA_STAGE(1, (t + 3) * 64), VM4);
    }
    FA_TILE(0, NOPS, VM0);        // tile 62; drain tile-63 loads
    FA_TILE(1, NOPS, NOPS);       // tile 63; nothing in flight

    // epilogue: transpose O^T -> O via per-wave LDS scratch, then coalesced write
    __syncthreads();
    u16* scratch = lds_all + wid * 2048;     // [q 32][d 64]
#pragma unroll
    for (int mtQ = 0; mtQ < 2; ++mtQ) {
        float rl = 1.f / lacc[mtQ][0];
#pragma unroll
        for (int dt = 0; dt < 4; ++dt) {
            uint2 ov;
            ov.x = pk2bf(o[mtQ][dt][0] * rl, o[mtQ][dt][1] * rl);
            ov.y = pk2bf(o[mtQ][dt][2] * rl, o[mtQ][dt][3] * rl);
            *(uint2*)&scratch[(mtQ * 16 + l15) * 64 + dt * 16 + quad * 4] = ov;
        }
    }
#pragma unroll
    for (int p = 0; p < 4; ++p) {
        int q_local = p * 8 + (lane >> 3);
        int dcol = (lane & 7) * 8;
        bf16x8 v = *(const bf16x8*)&scratch[q_local * 64 + dcol];
        *(bf16x8*)&O[(size_t)(q0 + q_local) * INNER + h * 64 + dcol] = v;
    }
}

extern "C" void kernel_launch(void* const* d_in, const int* in_sizes, int n_in,
                              void* d_out, int out_size, void* d_ws, size_t ws_size,
                              hipStream_t stream) {
    const float* x     = (const float*)d_in[0];
    const float* pe    = (const float*)d_in[1];
    const float* w_qkv = (const float*)d_in[2];
    const float* w_out = (const float*)d_in[3];
    const float* ln_g  = (const float*)d_in[4];
    const float* ln_b  = (const float*)d_in[5];
    float* out = (float*)d_out;

    char* ws = (char*)d_ws;
    u16* xn  = (u16*)ws;  ws += (size_t)N_TOK * DMODEL * 2;
    u16* wq  = (u16*)ws;  ws += (size_t)3 * INNER * DMODEL * 2;
    u16* wo  = (u16*)ws;  ws += (size_t)DMODEL * INNER * 2;
    u16* qkv = (u16*)ws;  ws += (size_t)N_TOK * DMODEL * 2;
    u16* Qr  = (u16*)ws;  ws += (size_t)NH * N_TOK * DHEAD * 2;
    u16* Kr  = (u16*)ws;  ws += (size_t)NH * N_TOK * DHEAD * 2;
    u16* Vt  = (u16*)ws;  ws += (size_t)NH * DHEAD * N_TOK * 2;
    u16* Ob  = (u16*)ws;  ws += (size_t)N_TOK * INNER * 2;

    ln_kernel<<<N_TOK, 256, 0, stream>>>(x, ln_g, ln_b, xn);
    {
        int n4 = 3 * INNER * DMODEL / 4;
        cvt_bf16<<<(n4 + 255) / 256, 256, 0, stream>>>(w_qkv, wq, n4);
    }
    {
        int n4 = DMODEL * INNER / 4;
        cvt_bf16<<<(n4 + 255) / 256, 256, 0, stream>>>(w_out, wo, n4);
    }
    gemm256<1><<<dim3((N_TOK / 256) * (DMODEL / 256)), 512, 0, stream>>>(xn, wq, qkv, N_TOK, DMODEL, DMODEL);
    rope_qk<<<N_TOK, 256, 0, stream>>>(qkv, pe, Qr, Kr);
    v_transpose<<<dim3(N_TOK / 64, NH), 256, 0, stream>>>(qkv, Vt);
    flash_attn<<<dim3(N_TOK / 128, NH), 256, 0, stream>>>(Qr, Kr, Vt, Ob);
    gemm256<0><<<dim3((N_TOK / 256) * (DMODEL / 256)), 512, 0, stream>>>(Ob, wo, out, N_TOK, DMODEL, INNER);
}

// Round 4
// 349.187 us; speedup vs baseline: 1.1527x; 1.0356x over previous
//
#include <hip/hip_runtime.h>
#include <hip/hip_bf16.h>

typedef unsigned short u16;
typedef __attribute__((ext_vector_type(8))) short bf16x8;
typedef __attribute__((ext_vector_type(4))) float f32x4;

#define N_TOK 4096
#define DMODEL 3072
#define NH 16
#define DHEAD 64
#define INNER 1024
#define SCALE_LOG2E 0.18033688011112042f  /* (1/8) * log2(e) */

__device__ __forceinline__ u16 f2bf(float f) {
    union { float f; unsigned u; } un; un.f = f;
    unsigned r = un.u + 0x7fffu + ((un.u >> 16) & 1u);
    return (u16)(r >> 16);
}
__device__ __forceinline__ float bf2f(u16 u) {
    union { unsigned u; float f; } x; x.u = ((unsigned)u) << 16; return x.f;
}
// pack two f32 -> two bf16 (round-half-up) in 3 VALU ops; a -> low 16
__device__ __forceinline__ unsigned pk2bf(float a, float b) {
    union { float f; unsigned u; } ua, ub; ua.f = a; ub.f = b;
    return __builtin_amdgcn_perm(ub.u + 0x8000u, ua.u + 0x8000u, 0x07060302u);
}
__device__ __forceinline__ void load_lds16(const u16* g, u16* l) {
    __builtin_amdgcn_global_load_lds(
        (const __attribute__((address_space(1))) unsigned int*)g,
        (__attribute__((address_space(3))) unsigned int*)l, 16, 0, 0);
}

// Build PV B-operand in-register from packed exp2(S^T) words.
// Inputs: u0,u1 = key pairs (4q+0,1)/(4q+2,3) of lower 16 keys (s[lo]);
//         w0,w1 = same for upper 16 keys (s[hi]).
// Output: lane (l15,quad) holds keys [8*quad, 8*quad+8) for col q=l15.
// swap32: new0={old0.lo,old1.lo}; swap16: new0=[o0@g0,o1@g0,o0@g2,o1@g2].
__device__ __forceinline__ bf16x8 build_bp(unsigned u0, unsigned u1,
                                           unsigned w0, unsigned w1) {
    auto a = __builtin_amdgcn_permlane32_swap(u0, w0, false, false);
    auto b = __builtin_amdgcn_permlane16_swap(a[0], a[1], false, false);
    auto c = __builtin_amdgcn_permlane32_swap(u1, w1, false, false);
    auto d = __builtin_amdgcn_permlane16_swap(c[0], c[1], false, false);
    union { unsigned w[4]; bf16x8 v; } r;
    r.w[0] = b[0]; r.w[1] = d[0]; r.w[2] = b[1]; r.w[3] = d[1];
    return r.v;
}

// ---------------- LayerNorm: x f32 [4096,3072] -> xn bf16 ----------------
__global__ __launch_bounds__(256) void ln_kernel(const float* __restrict__ x,
                                                 const float* __restrict__ g,
                                                 const float* __restrict__ b,
                                                 u16* __restrict__ xn) {
    int row = blockIdx.x;
    int tid = threadIdx.x;
    const float4* xr = (const float4*)(x + (size_t)row * DMODEL);
    float4 v[3];
    float s = 0.f, ss = 0.f;
#pragma unroll
    for (int i = 0; i < 3; ++i) {
        v[i] = xr[i * 256 + tid];
        s  += v[i].x + v[i].y + v[i].z + v[i].w;
        ss += v[i].x * v[i].x + v[i].y * v[i].y + v[i].z * v[i].z + v[i].w * v[i].w;
    }
#pragma unroll
    for (int off = 32; off; off >>= 1) {
        s  += __shfl_xor(s, off);
        ss += __shfl_xor(ss, off);
    }
    __shared__ float red[8];
    int wid = tid >> 6, lane = tid & 63;
    if (lane == 0) { red[wid] = s; red[wid + 4] = ss; }
    __syncthreads();
    s  = red[0] + red[1] + red[2] + red[3];
    ss = red[4] + red[5] + red[6] + red[7];
    float mean = s * (1.f / DMODEL);
    float var  = ss * (1.f / DMODEL) - mean * mean;
    float rstd = rsqrtf(var + 1e-5f);
    ushort4* orow = (ushort4*)(xn + (size_t)row * DMODEL);
#pragma unroll
    for (int i = 0; i < 3; ++i) {
        float4 gg = ((const float4*)g)[i * 256 + tid];
        float4 bb = ((const float4*)b)[i * 256 + tid];
        ushort4 o;
        o.x = f2bf((v[i].x - mean) * rstd * gg.x + bb.x);
        o.y = f2bf((v[i].y - mean) * rstd * gg.y + bb.y);
        o.z = f2bf((v[i].z - mean) * rstd * gg.z + bb.z);
        o.w = f2bf((v[i].w - mean) * rstd * gg.w + bb.w);
        orow[i * 256 + tid] = o;
    }
}

// ---------------- f32 -> bf16 convert ----------------
__global__ __launch_bounds__(256) void cvt_bf16(const float* __restrict__ in,
                                                u16* __restrict__ out, int n4) {
    int i = blockIdx.x * 256 + threadIdx.x;
    if (i < n4) {
        float4 v = ((const float4*)in)[i];
        ushort4 o;
        o.x = f2bf(v.x); o.y = f2bf(v.y); o.z = f2bf(v.z); o.w = f2bf(v.w);
        ((ushort4*)out)[i] = o;
    }
}

// ============ GEMM 256x256 8-phase (T2+T3+T4+T5), C = A * B^T ============
// (unchanged from R2 — verified; MfmaUtil up, both gemms now < flash_attn)

#define VM6 asm volatile("s_waitcnt vmcnt(6)" ::: "memory")
#define VM4 asm volatile("s_waitcnt vmcnt(4)" ::: "memory")
#define VM0 asm volatile("s_waitcnt vmcnt(0)" ::: "memory")
#define LGK8 asm volatile("s_waitcnt lgkmcnt(8)" ::: "memory")
#define NOPS ((void)0)

#define ST_A(d, h, t) do { \
    load_lds16(pA##h##0 + (size_t)(t) * 64, &lds[(d) * 16384 + (h) * 8192 + dq]); \
    load_lds16(pA##h##1 + (size_t)(t) * 64, &lds[(d) * 16384 + (h) * 8192 + dq + 512]); \
  } while (0)
#define ST_B(d, h, t) do { \
    load_lds16(pB##h##0 + (size_t)(t) * 64, &lds[32768 + (d) * 16384 + (h) * 8192 + dq]); \
    load_lds16(pB##h##1 + (size_t)(t) * 64, &lds[32768 + (d) * 16384 + (h) * 8192 + dq + 512]); \
  } while (0)

#define PHASE(d, p, STAGE, PRE, POST) do { \
    bf16x8 afr[2][2]; \
    if ((p) == 0) { \
      _Pragma("unroll") for (int nf = 0; nf < 4; ++nf) { \
        bfr[nf][0] = *(const bf16x8*)&lds[(d) * 16384 + baseB + nf * 1024 + c0]; \
        bfr[nf][1] = *(const bf16x8*)&lds[(d) * 16384 + baseB + nf * 1024 + c1]; \
      } \
    } \
    _Pragma("unroll") for (int mfl = 0; mfl < 2; ++mfl) { \
      afr[mfl][0] = *(const bf16x8*)&lds[(d) * 16384 + (p) * 4096 + mfl * 1024 + baseA + c0]; \
      afr[mfl][1] = *(const bf16x8*)&lds[(d) * 16384 + (p) * 4096 + mfl * 1024 + baseA + c1]; \
    } \
    STAGE; \
    PRE; \
    __builtin_amdgcn_s_barrier(); \
    asm volatile("s_waitcnt lgkmcnt(0)" ::: "memory"); \
    __builtin_amdgcn_sched_barrier(0); \
    __builtin_amdgcn_s_setprio(1); \
    _Pragma("unroll") for (int mfl = 0; mfl < 2; ++mfl) \
      _Pragma("unroll") for (int nf = 0; nf < 4; ++nf) { \
        acc[(p) * 2 + mfl][nf] = __builtin_amdgcn_mfma_f32_16x16x32_bf16(afr[mfl][0], bfr[nf][0], acc[(p) * 2 + mfl][nf], 0, 0, 0); \
        acc[(p) * 2 + mfl][nf] = __builtin_amdgcn_mfma_f32_16x16x32_bf16(afr[mfl][1], bfr[nf][1], acc[(p) * 2 + mfl][nf], 0, 0, 0); \
      } \
    __builtin_amdgcn_s_setprio(0); \
    POST; \
    __builtin_amdgcn_s_barrier(); \
  } while (0)

template <int CBF16>
__global__ __launch_bounds__(512, 2) void gemm256(const u16* __restrict__ A,
                                                  const u16* __restrict__ B,
                                                  void* __restrict__ C,
                                                  int M, int Nn, int K) {
    __shared__ u16 lds[65536];   // A: [2][256][64] @0 ; B: same @32768 (128 KiB)
    const int tid = threadIdx.x;
    const int lane = tid & 63, wid = tid >> 6;
    const int wm = wid >> 2, wn = wid & 3;
    const int l15 = lane & 15, quad = lane >> 4;
    const int sw = l15 & 7;

    // XCD-aware bijective swizzle (gridDim.x % 8 == 0)
    int nbx = Nn >> 8;
    int cpx = gridDim.x >> 3;
    int wg = (blockIdx.x & 7) * cpx + (blockIdx.x >> 3);
    int m0 = (wg / nbx) << 8, n0 = (wg % nbx) << 8;

    // per-thread ds_read bases (u16 units) and swizzled chunk offsets
    const int baseA = wm * 2048 + l15 * 64;
    const int baseB = 32768 + wn * 4096 + l15 * 64;
    const int c0 = (quad ^ sw) * 8;
    const int c1 = ((4 + quad) ^ sw) * 8;
    const int dq = wid * 1024;                 // stage LDS base (j adds 512)

    // stage source pointers: LDS row ell -> global row, pre-swizzled col
    const u16 *pA00, *pA01, *pA10, *pA11, *pB00, *pB01, *pB10, *pB11;
    {
        int scol = ((lane & 7) ^ (lane >> 3)) * 8;
#define MKSRC(h, j, PA, PB) { \
        int ell = (h) * 128 + (wid * 2 + (j)) * 8 + (lane >> 3); \
        int g = ell >> 6, wmh = (ell >> 5) & 1, r = ell & 31; \
        PA = A + (size_t)(m0 + wmh * 128 + g * 32 + r) * K + scol; \
        PB = B + (size_t)(n0 + ell) * K + scol; }
        MKSRC(0, 0, pA00, pB00) MKSRC(0, 1, pA01, pB01)
        MKSRC(1, 0, pA10, pB10) MKSRC(1, 1, pA11, pB11)
#undef MKSRC
    }

    f32x4 acc[8][4];
    f32x4 zero4 = {0.f, 0.f, 0.f, 0.f};
#pragma unroll
    for (int i = 0; i < 8; ++i)
#pragma unroll
        for (int j = 0; j < 4; ++j) acc[i][j] = zero4;
    bf16x8 bfr[4][2];

    // prologue: tile0 (4 halves) -> buf0, tile1 (B0,B1,A0) -> buf1
    ST_B(0, 0, 0); ST_B(0, 1, 0); ST_A(0, 0, 0); ST_A(0, 1, 0);
    ST_B(1, 0, 1); ST_B(1, 1, 1); ST_A(1, 0, 1);
    VM6;                                   // tile0 landed; 3 halves in flight
    __builtin_amdgcn_s_barrier();

    const int NIT = (K >> 7) - 1;          // T/2 - 1 iterations
    for (int i = 0; i < NIT; ++i) {
        int t = 2 * i;
        PHASE(0, 0, ST_A(1, 1, t + 1), LGK8, NOPS);
        PHASE(0, 1, ST_B(0, 0, t + 2), NOPS, NOPS);
        PHASE(0, 2, ST_B(0, 1, t + 2), NOPS, NOPS);
        PHASE(0, 3, ST_A(0, 0, t + 2), NOPS, VM6);
        PHASE(1, 0, ST_A(0, 1, t + 2), LGK8, NOPS);
        PHASE(1, 1, ST_B(1, 0, t + 3), NOPS, NOPS);
        PHASE(1, 2, ST_B(1, 1, t + 3), NOPS, NOPS);
        PHASE(1, 3, ST_A(1, 0, t + 3), NOPS, VM6);
    }
    {   // epilogue: tiles T-2 (buf0), T-1 (buf1); only (T-1).A1 left to stage
        int T = K >> 6;
        PHASE(0, 0, ST_A(1, 1, T - 1), LGK8, NOPS);
        PHASE(0, 1, NOPS, NOPS, NOPS);
        PHASE(0, 2, NOPS, NOPS, NOPS);
        PHASE(0, 3, NOPS, NOPS, VM0);
        PHASE(1, 0, NOPS, LGK8, NOPS);
        PHASE(1, 1, NOPS, NOPS, NOPS);
        PHASE(1, 2, NOPS, NOPS, NOPS);
        PHASE(1, 3, NOPS, NOPS, NOPS);
    }

    // C write: rr = m0 + wm*128 + mf*16 + quad*4 + r ; cc = n0 + wn*64 + nf*16 + l15
#pragma unroll
    for (int mf = 0; mf < 8; ++mf)
#pragma unroll
        for (int nf = 0; nf < 4; ++nf)
#pragma unroll
            for (int r = 0; r < 4; ++r) {
                int rr = m0 + wm * 128 + mf * 16 + quad * 4 + r;
                int cc = n0 + wn * 64 + nf * 16 + l15;
                if (CBF16)
                    ((u16*)C)[(size_t)rr * Nn + cc] = f2bf(acc[mf][nf][r]);
                else
                    ((float*)C)[(size_t)rr * Nn + cc] = acc[mf][nf][r];
            }
}

// ---------------- RoPE on q,k + reshape to [H,N,DH] ----------------
// Q is pre-scaled by (1/8)*log2(e) so flash's exp2 needs no multiply.
__global__ __launch_bounds__(256) void rope_qk(const u16* __restrict__ qkv,
                                               const float* __restrict__ pe,
                                               u16* __restrict__ Qr,
                                               u16* __restrict__ Kr) {
    int n = blockIdx.x;
    int tid = threadIdx.x;
    const u16* qrow = qkv + (size_t)n * DMODEL;
    const float4* pen = (const float4*)(pe + (size_t)n * 128);
#pragma unroll
    for (int it = 0; it < 2; ++it) {
        int p = it * 256 + tid;      // pair index 0..511
        int h = p >> 5, i = p & 31;
        float4 w = pen[i];
        size_t obase = ((size_t)h * N_TOK + n) * DHEAD + 2 * i;
        unsigned qq = *(const unsigned*)&qrow[h * 64 + 2 * i];
        float q0 = bf2f((u16)qq), q1 = bf2f((u16)(qq >> 16));
        *(unsigned*)&Qr[obase] = pk2bf((w.x * q0 + w.y * q1) * SCALE_LOG2E,
                                       (w.z * q0 + w.w * q1) * SCALE_LOG2E);
        unsigned kk = *(const unsigned*)&qrow[INNER + h * 64 + 2 * i];
        float k0 = bf2f((u16)kk), k1 = bf2f((u16)(kk >> 16));
        *(unsigned*)&Kr[obase] = pk2bf(w.x * k0 + w.y * k1, w.z * k0 + w.w * k1);
    }
}

// ---------------- V transpose: Vt[h][d][n] = qkv[n][2048 + h*64 + d] ------
__global__ __launch_bounds__(256) void v_transpose(const u16* __restrict__ qkv,
                                                   u16* __restrict__ Vt) {
    __shared__ u16 t[64][65];
    int n0 = blockIdx.x * 64;
    int h = blockIdx.y;
    int tid = threadIdx.x;
#pragma unroll
    for (int it = 0; it < 4; ++it) {
        int nr = it * 16 + (tid >> 4);
        int dc = (tid & 15) * 4;
        ushort4 v = *(const ushort4*)&qkv[(size_t)(n0 + nr) * DMODEL + 2 * INNER + h * 64 + dc];
        t[dc + 0][nr] = v.x; t[dc + 1][nr] = v.y; t[dc + 2][nr] = v.z; t[dc + 3][nr] = v.w;
    }
    __syncthreads();
#pragma unroll
    for (int it = 0; it < 4; ++it) {
        int dr = it * 16 + (tid >> 4);
        int nc = (tid & 15) * 4;
        ushort4 v;
        v.x = t[dr][nc]; v.y = t[dr][nc + 1]; v.z = t[dr][nc + 2]; v.w = t[dr][nc + 3];
        *(ushort4*)&Vt[((size_t)h * 64 + dr) * N_TOK + n0 + nc] = v;
    }
}

// ---------------- Flash attention: in-register P exchange -----------------
// grid (32 qtiles, 16 heads); 256 thr = 4 waves; wave owns 32 q-rows.
// K/V double-buffered (2x16KB), counted vmcnt(4) pipeline (R3).
// R4: P stays in registers — after QK^T + exp2, pack to bf16 and rearrange
// across quads via permlane32_swap + permlane16_swap (fixed l15=q) to form
// the PV B-operand directly. No Ps LDS, no ds round-trip, no bank conflicts.

#define FA_STAGE(d, kt) do { \
    load_lds16(&Kh[(size_t)((kt) + rbase + rowoff) * DHEAD + csw], &lds_all[(d) * 8192 + rbase * 64]); \
    load_lds16(&Kh[(size_t)((kt) + rbase + 8 + rowoff) * DHEAD + csw], &lds_all[(d) * 8192 + (rbase + 8) * 64]); \
    load_lds16(&Vh[(size_t)(rbase + rowoff) * N_TOK + (kt) + csw], &lds_all[(d) * 8192 + 4096 + rbase * 64]); \
    load_lds16(&Vh[(size_t)(rbase + 8 + rowoff) * N_TOK + (kt) + csw], &lds_all[(d) * 8192 + 4096 + (rbase + 8) * 64]); \
  } while (0)

#define FA_TILE(d, STAGE_STMT, WAIT_STMT) do { \
    bf16x8 bk[4][2], av[4][2]; \
    _Pragma("unroll") for (int tt = 0; tt < 4; ++tt) \
      _Pragma("unroll") for (int kc = 0; kc < 2; ++kc) { \
        int off = (d) * 8192 + (tt * 16 + l15) * 64 + (((kc * 4 + quad) ^ sw) * 8); \
        bk[tt][kc] = *(const bf16x8*)&lds_all[off]; \
        av[tt][kc] = *(const bf16x8*)&lds_all[off + 4096]; \
      } \
    asm volatile("s_waitcnt lgkmcnt(0)" ::: "memory"); \
    __builtin_amdgcn_sched_barrier(0); \
    __builtin_amdgcn_s_barrier(); \
    __builtin_amdgcn_sched_barrier(0); \
    STAGE_STMT; \
    _Pragma("unroll") for (int mtQ = 0; mtQ < 2; ++mtQ) { \
      f32x4 s[4]; \
      _Pragma("unroll") for (int ntK = 0; ntK < 4; ++ntK) { \
        f32x4 t0 = __builtin_amdgcn_mfma_f32_16x16x32_bf16(bk[ntK][0], aq[mtQ][0], zero4, 0, 0, 0); \
        s[ntK] = __builtin_amdgcn_mfma_f32_16x16x32_bf16(bk[ntK][1], aq[mtQ][1], t0, 0, 0, 0); \
      } \
      unsigned pw[4][2]; \
      _Pragma("unroll") for (int ntK = 0; ntK < 4; ++ntK) { \
        pw[ntK][0] = pk2bf(__builtin_amdgcn_exp2f(s[ntK][0]), __builtin_amdgcn_exp2f(s[ntK][1])); \
        pw[ntK][1] = pk2bf(__builtin_amdgcn_exp2f(s[ntK][2]), __builtin_amdgcn_exp2f(s[ntK][3])); \
      } \
      bf16x8 bp0 = build_bp(pw[0][0], pw[0][1], pw[1][0], pw[1][1]); \
      bf16x8 bp1 = build_bp(pw[2][0], pw[2][1], pw[3][0], pw[3][1]); \
      lacc[mtQ] = __builtin_amdgcn_mfma_f32_16x16x32_bf16(ones, bp0, lacc[mtQ], 0, 0, 0); \
      lacc[mtQ] = __builtin_amdgcn_mfma_f32_16x16x32_bf16(ones, bp1, lacc[mtQ], 0, 0, 0); \
      _Pragma("unroll") for (int dt = 0; dt < 4; ++dt) { \
        o[mtQ][dt] = __builtin_amdgcn_mfma_f32_16x16x32_bf16(av[dt][0], bp0, o[mtQ][dt], 0, 0, 0); \
        o[mtQ][dt] = __builtin_amdgcn_mfma_f32_16x16x32_bf16(av[dt][1], bp1, o[mtQ][dt], 0, 0, 0); \
      } \
    } \
    WAIT_STMT; \
    __builtin_amdgcn_s_barrier(); \
    __builtin_amdgcn_sched_barrier(0); \
  } while (0)

__global__ __launch_bounds__(256, 2) void flash_attn(const u16* __restrict__ Q,
                                                     const u16* __restrict__ K,
                                                     const u16* __restrict__ Vt,
                                                     u16* __restrict__ O) {
    __shared__ u16 lds_all[16384];           // 32 KB: K/V dbuf 2x16KB (no Ps)
    int tid = threadIdx.x, lane = tid & 63, wid = tid >> 6;
    int l15 = lane & 15, quad = lane >> 4;
    int sw = l15 & 7;
    int h = blockIdx.y;
    int q0 = blockIdx.x * 128 + wid * 32;
    const u16* Qh = Q + (size_t)h * N_TOK * DHEAD;
    const u16* Kh = K + (size_t)h * N_TOK * DHEAD;
    const u16* Vh = Vt + (size_t)h * DHEAD * N_TOK;

    f32x4 zero4 = {0.f, 0.f, 0.f, 0.f};
    bf16x8 ones;
#pragma unroll
    for (int i = 0; i < 8; ++i) ones[i] = (short)0x3F80;  // bf16 1.0

    // Q fragments (B operand): B[n=q=l15][k=dhead]
    bf16x8 aq[2][2];
#pragma unroll
    for (int mtQ = 0; mtQ < 2; ++mtQ)
#pragma unroll
        for (int kc = 0; kc < 2; ++kc)
            aq[mtQ][kc] = *(const bf16x8*)&Qh[(size_t)(q0 + mtQ * 16 + l15) * DHEAD + kc * 32 + quad * 8];

    f32x4 o[2][4], lacc[2];
#pragma unroll
    for (int mtQ = 0; mtQ < 2; ++mtQ) {
#pragma unroll
        for (int dt = 0; dt < 4; ++dt) o[mtQ][dt] = zero4;
        lacc[mtQ] = zero4;
    }

    // staging: wave stages rows [wid*16, wid*16+16); XOR swizzle on global col
    int rbase = wid * 16;
    int rowoff = lane >> 3;                      // 0..7
    int csw = ((lane & 7) ^ rowoff) * 8;         // swizzled source column (u16)

    // prologue: tiles 0,1 -> bufs 0,1 (8 loads); wait tile0 (4 newest remain)
    FA_STAGE(0, 0);
    FA_STAGE(1, 64);
    VM4;
    __builtin_amdgcn_s_barrier();
    __builtin_amdgcn_sched_barrier(0);

    for (int t = 0; t < 62; t += 2) {
        FA_TILE(0, FA_STAGE(0, (t + 2) * 64), VM4);
        FA_TILE(1, FA_STAGE(1, (t + 3) * 64), VM4);
    }
    FA_TILE(0, NOPS, VM0);        // tile 62; drain tile-63 loads
    FA_TILE(1, NOPS, NOPS);       // tile 63; nothing in flight

    // epilogue: transpose O^T -> O via per-wave LDS scratch, then coalesced write
    __syncthreads();
    u16* scratch = lds_all + wid * 2048;     // [q 32][d 64]
#pragma unroll
    for (int mtQ = 0; mtQ < 2; ++mtQ) {
        float rl = 1.f / lacc[mtQ][0];
#pragma unroll
        for (int dt = 0; dt < 4; ++dt) {
            uint2 ov;
            ov.x = pk2bf(o[mtQ][dt][0] * rl, o[mtQ][dt][1] * rl);
            ov.y = pk2bf(o[mtQ][dt][2] * rl, o[mtQ][dt][3] * rl);
            *(uint2*)&scratch[(mtQ * 16 + l15) * 64 + dt * 16 + quad * 4] = ov;
        }
    }
#pragma unroll
    for (int p = 0; p < 4; ++p) {
        int q_local = p * 8 + (lane >> 3);
        int dcol = (lane & 7) * 8;
        bf16x8 v = *(const bf16x8*)&scratch[q_local * 64 + dcol];
        *(bf16x8*)&O[(size_t)(q0 + q_local) * INNER + h * 64 + dcol] = v;
    }
}

extern "C" void kernel_launch(void* const* d_in, const int* in_sizes, int n_in,
                              void* d_out, int out_size, void* d_ws, size_t ws_size,
                              hipStream_t stream) {
    const float* x     = (const float*)d_in[0];
    const float* pe    = (const float*)d_in[1];
    const float* w_qkv = (const float*)d_in[2];
    const float* w_out = (const float*)d_in[3];
    const float* ln_g  = (const float*)d_in[4];
    const float* ln_b  = (const float*)d_in[5];
    float* out = (float*)d_out;

    char* ws = (char*)d_ws;
    u16* xn  = (u16*)ws;  ws += (size_t)N_TOK * DMODEL * 2;
    u16* wq  = (u16*)ws;  ws += (size_t)3 * INNER * DMODEL * 2;
    u16* wo  = (u16*)ws;  ws += (size_t)DMODEL * INNER * 2;
    u16* qkv = (u16*)ws;  ws += (size_t)N_TOK * DMODEL * 2;
    u16* Qr  = (u16*)ws;  ws += (size_t)NH * N_TOK * DHEAD * 2;
    u16* Kr  = (u16*)ws;  ws += (size_t)NH * N_TOK * DHEAD * 2;
    u16* Vt  = (u16*)ws;  ws += (size_t)NH * DHEAD * N_TOK * 2;
    u16* Ob  = (u16*)ws;  ws += (size_t)N_TOK * INNER * 2;

    ln_kernel<<<N_TOK, 256, 0, stream>>>(x, ln_g, ln_b, xn);
    {
        int n4 = 3 * INNER * DMODEL / 4;
        cvt_bf16<<<(n4 + 255) / 256, 256, 0, stream>>>(w_qkv, wq, n4);
    }
    {
        int n4 = DMODEL * INNER / 4;
        cvt_bf16<<<(n4 + 255) / 256, 256, 0, stream>>>(w_out, wo, n4);
    }
    gemm256<1><<<dim3((N_TOK / 256) * (DMODEL / 256)), 512, 0, stream>>>(xn, wq, qkv, N_TOK, DMODEL, DMODEL);
    rope_qk<<<N_TOK, 256, 0, stream>>>(qkv, pe, Qr, Kr);
    v_transpose<<<dim3(N_TOK / 64, NH), 256, 0, stream>>>(qkv, Vt);
    flash_attn<<<dim3(N_TOK / 128, NH), 256, 0, stream>>>(Qr, Kr, Vt, Ob);
    gemm256<0><<<dim3((N_TOK / 256) * (DMODEL / 256)), 512, 0, stream>>>(Ob, wo, out, N_TOK, DMODEL, INNER);
}